// Round 2
// baseline (1255.126 us; speedup 1.0000x reference)
//
#include <hip/hip_runtime.h>
#include <hip/hip_bf16.h>

// Problem constants (from reference)
#define N_NODES 100000
#define N_EDGES 400000
#define IN_F    128
#define HID     1024
#define OUT_F   64

// ---------------- degree / norm kernels ----------------

__global__ void init_deg_kernel(float* __restrict__ deg, int n) {
    int i = blockIdx.x * blockDim.x + threadIdx.x;
    if (i < n) deg[i] = 1.0f;   // self-loop weight
}

__global__ void deg_accum_kernel(const int* __restrict__ dst, const float* __restrict__ w,
                                 float* __restrict__ deg, int E) {
    int e = blockIdx.x * blockDim.x + threadIdx.x;
    if (e < E) atomicAdd(&deg[dst[e]], w[e]);
}

__global__ void rsqrt_inplace_kernel(float* __restrict__ deg, int n) {
    int i = blockIdx.x * blockDim.x + threadIdx.x;
    if (i < n) deg[i] = rsqrtf(deg[i]);   // deg >= 1 always (self-loop)
}

__global__ void compute_norm_kernel(const int* __restrict__ src, const int* __restrict__ dst,
                                    const float* __restrict__ w, const float* __restrict__ dinv,
                                    float* __restrict__ norm, int E) {
    int e = blockIdx.x * blockDim.x + threadIdx.x;
    if (e < E) norm[e] = dinv[src[e]] * w[e] * dinv[dst[e]];
}

// ---------------- aggregation kernels ----------------

// out[i][f] = dinv[i]^2 * feat[i][f] + bias[f]   (self-loop term + optional bias)
template<int LOGF>
__global__ void selfloop_init_kernel(const float* __restrict__ dinv, const float* __restrict__ feat,
                                     const float* __restrict__ bias, float* __restrict__ out, int n) {
    const int F = 1 << LOGF;
    long idx = (long)blockIdx.x * blockDim.x + threadIdx.x;
    long total = (long)n << LOGF;
    if (idx < total) {
        int i = (int)(idx >> LOGF);
        int f = (int)(idx & (F - 1));
        float di = dinv[i];
        float v = di * di * feat[idx];
        if (bias) v += bias[f];
        out[idx] = v;
    }
}

// out[dst[e]][f] += norm[e] * feat[src[e]][f]
template<int LOGF>
__global__ void scatter_edges_kernel(const int* __restrict__ src, const int* __restrict__ dst,
                                     const float* __restrict__ norm, const float* __restrict__ feat,
                                     float* __restrict__ out, int E) {
    const int F = 1 << LOGF;
    long idx = (long)blockIdx.x * blockDim.x + threadIdx.x;
    long total = (long)E << LOGF;
    if (idx < total) {
        int e = (int)(idx >> LOGF);
        int f = (int)(idx & (F - 1));
        int s = src[e];
        int d = dst[e];
        float nv = norm[e];
        atomicAdd(&out[(long)d * F + f], nv * feat[(long)s * F + f]);
    }
}

// ---------------- fused MLP: T = relu(A @ W1 + b1) @ W2 ----------------
// A:[M,128], W1:[128,1024], W2:[1024,64], T:[M,64]
// Per block: 64 rows. 16 chunks of 64 HID cols; h chunk lives in LDS only.
// LDS: Xs 33.0K + Bs 17.0K + Hs 17.0K = 67 KB -> 2 blocks/CU.

__global__ __launch_bounds__(256) void fused_mlp_kernel(
    const float* __restrict__ A, const float* __restrict__ W1,
    const float* __restrict__ b1, const float* __restrict__ W2,
    float* __restrict__ T, int M)
{
    __shared__ float Xs[64][132];   // pad 132 (=4 mod 32, 16B-multiple stride)
    __shared__ float Bs[64][68];    // W1-half / W2 chunk
    __shared__ float Hs[64][68];    // relu(h) chunk

    const int tid = threadIdx.x;
    const int tx = tid & 15;        // output col group
    const int ty = tid >> 4;        // output row group
    const long bm = (long)blockIdx.x * 64;

    // ---- load A tile [64][128] ----
    {
        int row = tid >> 2;         // 0..63
        int c4  = tid & 3;          // 0..3
        long grow = bm + row;
        #pragma unroll
        for (int i = 0; i < 8; i++) {
            int col = (c4 + i * 4) * 4;
            float4 v = make_float4(0.f, 0.f, 0.f, 0.f);
            if (grow < M) v = *(const float4*)(A + grow * IN_F + col);
            Xs[row][col + 0] = v.x;
            Xs[row][col + 1] = v.y;
            Xs[row][col + 2] = v.z;
            Xs[row][col + 3] = v.w;
        }
    }

    float tacc[4][4] = {};

    const int lr  = tid >> 4;       // 0..15 (staging row base)
    const int lc4 = tid & 15;       // 0..15 (staging float4 col)

    for (int c = 0; c < 16; c++) {
        float hacc[4][4] = {};

        // ---- GEMM1: hacc += Xs @ W1[:, c*64:+64], K=128 in two halves ----
        #pragma unroll
        for (int kh = 0; kh < 2; kh++) {
            __syncthreads();        // prior Bs readers done
            #pragma unroll
            for (int i = 0; i < 4; i++) {
                int r = lr + i * 16;
                *(float4*)&Bs[r][lc4 * 4] =
                    *(const float4*)(W1 + (long)(kh * 64 + r) * HID + c * 64 + lc4 * 4);
            }
            __syncthreads();
            #pragma unroll
            for (int k = 0; k < 64; k++) {
                float a0 = Xs[ty * 4 + 0][kh * 64 + k];
                float a1 = Xs[ty * 4 + 1][kh * 64 + k];
                float a2 = Xs[ty * 4 + 2][kh * 64 + k];
                float a3 = Xs[ty * 4 + 3][kh * 64 + k];
                float4 b4 = *(const float4*)&Bs[k][tx * 4];
                float a[4] = {a0, a1, a2, a3};
                float b[4] = {b4.x, b4.y, b4.z, b4.w};
                #pragma unroll
                for (int m = 0; m < 4; m++)
                    #pragma unroll
                    for (int n = 0; n < 4; n++)
                        hacc[m][n] += a[m] * b[n];
            }
        }

        __syncthreads();            // GEMM1 Bs readers done

        // ---- stage W2 chunk + write relu(h) chunk ----
        #pragma unroll
        for (int i = 0; i < 4; i++) {
            int r = lr + i * 16;
            *(float4*)&Bs[r][lc4 * 4] =
                *(const float4*)(W2 + (long)(c * 64 + r) * OUT_F + lc4 * 4);
        }
        #pragma unroll
        for (int m = 0; m < 4; m++) {
            float4 v;
            v.x = fmaxf(hacc[m][0] + b1[c * 64 + tx * 4 + 0], 0.f);
            v.y = fmaxf(hacc[m][1] + b1[c * 64 + tx * 4 + 1], 0.f);
            v.z = fmaxf(hacc[m][2] + b1[c * 64 + tx * 4 + 2], 0.f);
            v.w = fmaxf(hacc[m][3] + b1[c * 64 + tx * 4 + 3], 0.f);
            *(float4*)&Hs[ty * 4 + m][tx * 4] = v;
        }

        __syncthreads();            // Bs(W2) + Hs visible

        // ---- GEMM2: tacc += Hs @ W2chunk, K=64 ----
        #pragma unroll
        for (int k = 0; k < 64; k++) {
            float a0 = Hs[ty * 4 + 0][k];
            float a1 = Hs[ty * 4 + 1][k];
            float a2 = Hs[ty * 4 + 2][k];
            float a3 = Hs[ty * 4 + 3][k];
            float4 b4 = *(const float4*)&Bs[k][tx * 4];
            float a[4] = {a0, a1, a2, a3};
            float b[4] = {b4.x, b4.y, b4.z, b4.w};
            #pragma unroll
            for (int m = 0; m < 4; m++)
                #pragma unroll
                for (int n = 0; n < 4; n++)
                    tacc[m][n] += a[m] * b[n];
        }
    }

    // ---- store T tile ----
    #pragma unroll
    for (int m = 0; m < 4; m++) {
        long grow = bm + ty * 4 + m;
        if (grow < M) {
            float4 v;
            v.x = tacc[m][0]; v.y = tacc[m][1]; v.z = tacc[m][2]; v.w = tacc[m][3];
            *(float4*)(T + grow * OUT_F + tx * 4) = v;
        }
    }
}

// ---------------- launch ----------------

extern "C" void kernel_launch(void* const* d_in, const int* in_sizes, int n_in,
                              void* d_out, int out_size, void* d_ws, size_t ws_size,
                              hipStream_t stream) {
    const float* x   = (const float*)d_in[0];                 // [N, 128]
    const int*   src = (const int*)d_in[1];                   // edge_index[0]
    const int*   dst = ((const int*)d_in[1]) + N_EDGES;       // edge_index[1]
    const float* ew  = (const float*)d_in[2];                 // [E]
    const float* W1  = (const float*)d_in[3];                 // [128, 1024]
    const float* b1  = (const float*)d_in[4];                 // [1024]
    const float* W2  = (const float*)d_in[5];                 // [1024, 64]
    const float* b2  = (const float*)d_in[6];                 // [64]
    float* out = (float*)d_out;                               // [N, 64]

    // workspace layout (floats): total ~19.7M floats = 78.8 MB
    float* ws   = (float*)d_ws;
    float* dinv = ws;                       // 100000
    float* norm = ws + 100096;              // 400000
    float* xa   = ws + 500096;              // 100000*128 = 12.8M
    float* t    = ws + 13300096;            // 100000*64  = 6.4M

    const int B = 256;

    // 1. degree (with self-loop) -> dinv -> norm
    init_deg_kernel<<<(N_NODES + B - 1) / B, B, 0, stream>>>(dinv, N_NODES);
    deg_accum_kernel<<<(N_EDGES + B - 1) / B, B, 0, stream>>>(dst, ew, dinv, N_EDGES);
    rsqrt_inplace_kernel<<<(N_NODES + B - 1) / B, B, 0, stream>>>(dinv, N_NODES);
    compute_norm_kernel<<<(N_EDGES + B - 1) / B, B, 0, stream>>>(src, dst, ew, dinv, norm, N_EDGES);

    // 2. layer-1 aggregation on raw x (128 feats): xa = A_norm @ x
    {
        long total = (long)N_NODES << 7;
        selfloop_init_kernel<7><<<(int)((total + B - 1) / B), B, 0, stream>>>(dinv, x, nullptr, xa, N_NODES);
        total = (long)N_EDGES << 7;
        scatter_edges_kernel<7><<<(int)((total + B - 1) / B), B, 0, stream>>>(src, dst, norm, x, xa, N_EDGES);
    }

    // 3. t = relu(xa @ W1 + b1) @ W2   (fused, no h buffer)
    fused_mlp_kernel<<<(N_NODES + 63) / 64, 256, 0, stream>>>(xa, W1, b1, W2, t, N_NODES);

    // 4. layer-2 aggregation on t (64 feats): out = A_norm @ t + b2
    {
        long total = (long)N_NODES << 6;
        selfloop_init_kernel<6><<<(int)((total + B - 1) / B), B, 0, stream>>>(dinv, t, b2, out, N_NODES);
        total = (long)N_EDGES << 6;
        scatter_edges_kernel<6><<<(int)((total + B - 1) / B), B, 0, stream>>>(src, dst, norm, t, out, N_EDGES);
    }
}

// Round 3
// 568.993 us; speedup vs baseline: 2.2059x; 2.2059x over previous
//
#include <hip/hip_runtime.h>
#include <hip/hip_bf16.h>

// Problem constants (from reference)
#define N_NODES 100000
#define N_EDGES 400000
#define IN_F    128
#define HID     1024
#define OUT_F   64

typedef __attribute__((ext_vector_type(8))) short short8;
typedef __attribute__((ext_vector_type(4))) float floatx4;

__device__ inline unsigned short f2bf(float f) {   // RNE fp32 -> bf16
    unsigned int u = __float_as_uint(f);
    unsigned int r = u + 0x7FFF + ((u >> 16) & 1);
    return (unsigned short)(r >> 16);
}

// ---------------- degree / norm kernels ----------------

__global__ void init_deg_kernel(float* __restrict__ deg, int n) {
    int i = blockIdx.x * blockDim.x + threadIdx.x;
    if (i < n) deg[i] = 1.0f;   // self-loop weight
}

__global__ void deg_accum_kernel(const int* __restrict__ dst, const float* __restrict__ w,
                                 float* __restrict__ deg, int E) {
    int e = blockIdx.x * blockDim.x + threadIdx.x;
    if (e < E) atomicAdd(&deg[dst[e]], w[e]);
}

__global__ void rsqrt_inplace_kernel(float* __restrict__ deg, int n) {
    int i = blockIdx.x * blockDim.x + threadIdx.x;
    if (i < n) deg[i] = rsqrtf(deg[i]);
}

__global__ void compute_norm_kernel(const int* __restrict__ src, const int* __restrict__ dst,
                                    const float* __restrict__ w, const float* __restrict__ dinv,
                                    float* __restrict__ norm, int E) {
    int e = blockIdx.x * blockDim.x + threadIdx.x;
    if (e < E) norm[e] = dinv[src[e]] * w[e] * dinv[dst[e]];
}

// ---------------- aggregation kernels ----------------

template<int LOGF>
__global__ void selfloop_init_kernel(const float* __restrict__ dinv, const float* __restrict__ feat,
                                     const float* __restrict__ bias, float* __restrict__ out, int n) {
    const int F = 1 << LOGF;
    long idx = (long)blockIdx.x * blockDim.x + threadIdx.x;
    long total = (long)n << LOGF;
    if (idx < total) {
        int i = (int)(idx >> LOGF);
        int f = (int)(idx & (F - 1));
        float di = dinv[i];
        float v = di * di * feat[idx];
        if (bias) v += bias[f];
        out[idx] = v;
    }
}

template<int LOGF>
__global__ void scatter_edges_kernel(const int* __restrict__ src, const int* __restrict__ dst,
                                     const float* __restrict__ norm, const float* __restrict__ feat,
                                     float* __restrict__ out, int E) {
    const int F = 1 << LOGF;
    long idx = (long)blockIdx.x * blockDim.x + threadIdx.x;
    long total = (long)E << LOGF;
    if (idx < total) {
        int e = (int)(idx >> LOGF);
        int f = (int)(idx & (F - 1));
        int s = src[e];
        int d = dst[e];
        float nv = norm[e];
        atomicAdd(&out[(long)d * F + f], nv * feat[(long)s * F + f]);
    }
}

// ---------------- conversion kernels ----------------

// xa fp32 -> bf16, 4 elems per thread
__global__ void convert_x_kernel(const float* __restrict__ in, unsigned short* __restrict__ out, long n4) {
    long i = (long)blockIdx.x * blockDim.x + threadIdx.x;
    if (i < n4) {
        float4 v = *(const float4*)(in + i * 4);
        out[i * 4 + 0] = f2bf(v.x);
        out[i * 4 + 1] = f2bf(v.y);
        out[i * 4 + 2] = f2bf(v.z);
        out[i * 4 + 3] = f2bf(v.w);
    }
}

// W1[128][1024] -> W1T[1024][128] bf16
__global__ void convert_w1t_kernel(const float* __restrict__ W1, unsigned short* __restrict__ W1T) {
    int o = blockIdx.x * blockDim.x + threadIdx.x;   // 131072
    if (o < IN_F * HID) {
        int n = o >> 7, k = o & 127;
        W1T[o] = f2bf(W1[(long)k * HID + n]);
    }
}

// W2[1024][64] -> W2T[64][1024] bf16
__global__ void convert_w2t_kernel(const float* __restrict__ W2, unsigned short* __restrict__ W2T) {
    int o = blockIdx.x * blockDim.x + threadIdx.x;   // 65536
    if (o < HID * OUT_F) {
        int n = o >> 10, k = o & 1023;
        W2T[o] = f2bf(W2[(long)k * OUT_F + n]);
    }
}

// ---------------- fused MFMA MLP: T = relu(X @ W1 + b1) @ W2 ----------------
// X bf16 [M][128], W1T bf16 [1024][128], W2T bf16 [64][1024], T fp32 [M][64].
// Block: 256 thr = 4 waves, 128 rows. Wave w owns rows w*32 .. w*32+31 (2 row-tiles).
// mfma_f32_16x16x32_bf16: A lane(row=l&15, k=(l>>4)*8+j), B lane(col=l&15, same k),
// C/D lane(col=l&15, row=(l>>4)*4+reg).

#define MLP_BM 128

__global__ __launch_bounds__(256) void fused_mlp_mfma_kernel(
    const unsigned short* __restrict__ Xb, const unsigned short* __restrict__ W1T,
    const float* __restrict__ b1, const unsigned short* __restrict__ W2T,
    float* __restrict__ T, int M)
{
    __shared__ unsigned short Hs[128][72];   // pad 72 shorts = 144 B (16B-mult, conflict-light)

    const int tid = threadIdx.x;
    const int w   = tid >> 6;
    const int l   = tid & 63;
    const int lr  = l & 15;      // row (A/C) or col (B/C) within 16-tile
    const int lq  = l >> 4;      // k-quad
    const long bm = (long)blockIdx.x * MLP_BM;

    // ---- load X A-fragments: [rt][kt] ----
    short8 ax[2][4];
    #pragma unroll
    for (int rt = 0; rt < 2; rt++) {
        long row = bm + w * 32 + rt * 16 + lr;
        if (row < M) {
            const unsigned short* p = Xb + row * IN_F + lq * 8;
            #pragma unroll
            for (int kt = 0; kt < 4; kt++)
                ax[rt][kt] = *(const short8*)(p + kt * 32);
        } else {
            #pragma unroll
            for (int kt = 0; kt < 4; kt++)
                #pragma unroll
                for (int j = 0; j < 8; j++) ax[rt][kt][j] = 0;
        }
    }

    floatx4 tacc[2][4];
    #pragma unroll
    for (int rt = 0; rt < 2; rt++)
        #pragma unroll
        for (int nt = 0; nt < 4; nt++)
            tacc[rt][nt] = (floatx4)0.0f;

    for (int c = 0; c < 16; c++) {
        // ---- GEMM1: Hacc[2][4] = X(128 rows? this wave's 32) @ W1T chunk ----
        floatx4 hacc[2][4];
        #pragma unroll
        for (int rt = 0; rt < 2; rt++)
            #pragma unroll
            for (int nt = 0; nt < 4; nt++)
                hacc[rt][nt] = (floatx4)0.0f;

        const unsigned short* w1p = W1T + (long)(c * 64 + lr) * IN_F + lq * 8;
        #pragma unroll
        for (int kt = 0; kt < 4; kt++) {
            #pragma unroll
            for (int nt = 0; nt < 4; nt++) {
                short8 bf = *(const short8*)(w1p + (long)nt * 16 * IN_F + kt * 32);
                hacc[0][nt] = __builtin_amdgcn_mfma_f32_16x16x32_bf16(ax[0][kt], bf, hacc[0][nt], 0, 0, 0);
                hacc[1][nt] = __builtin_amdgcn_mfma_f32_16x16x32_bf16(ax[1][kt], bf, hacc[1][nt], 0, 0, 0);
            }
        }

        __syncthreads();   // previous chunk's Hs readers done

        // ---- bias + relu + cvt bf16 -> Hs ----
        #pragma unroll
        for (int nt = 0; nt < 4; nt++) {
            float bb = b1[c * 64 + nt * 16 + lr];
            #pragma unroll
            for (int rt = 0; rt < 2; rt++) {
                #pragma unroll
                for (int r = 0; r < 4; r++) {
                    float v = hacc[rt][nt][r] + bb;
                    v = fmaxf(v, 0.0f);
                    Hs[w * 32 + rt * 16 + lq * 4 + r][nt * 16 + lr] = f2bf(v);
                }
            }
        }

        __syncthreads();   // Hs visible

        // ---- GEMM2: tacc += Hs @ W2T chunk ----
        const unsigned short* w2p = W2T + (long)lr * HID + c * 64 + lq * 8;
        #pragma unroll
        for (int kb = 0; kb < 2; kb++) {
            short8 b2f[4];
            #pragma unroll
            for (int nt = 0; nt < 4; nt++)
                b2f[nt] = *(const short8*)(w2p + (long)nt * 16 * HID + kb * 32);
            #pragma unroll
            for (int rt = 0; rt < 2; rt++) {
                short8 af = *(const short8*)&Hs[w * 32 + rt * 16 + lr][kb * 32 + lq * 8];
                #pragma unroll
                for (int nt = 0; nt < 4; nt++)
                    tacc[rt][nt] = __builtin_amdgcn_mfma_f32_16x16x32_bf16(af, b2f[nt], tacc[rt][nt], 0, 0, 0);
            }
        }
    }

    // ---- store T ----
    #pragma unroll
    for (int rt = 0; rt < 2; rt++) {
        #pragma unroll
        for (int r = 0; r < 4; r++) {
            long row = bm + w * 32 + rt * 16 + lq * 4 + r;
            if (row < M) {
                #pragma unroll
                for (int nt = 0; nt < 4; nt++)
                    T[row * OUT_F + nt * 16 + lr] = tacc[rt][nt][r];
            }
        }
    }
}

// ---------------- launch ----------------

extern "C" void kernel_launch(void* const* d_in, const int* in_sizes, int n_in,
                              void* d_out, int out_size, void* d_ws, size_t ws_size,
                              hipStream_t stream) {
    const float* x   = (const float*)d_in[0];                 // [N, 128]
    const int*   src = (const int*)d_in[1];                   // edge_index[0]
    const int*   dst = ((const int*)d_in[1]) + N_EDGES;       // edge_index[1]
    const float* ew  = (const float*)d_in[2];                 // [E]
    const float* W1  = (const float*)d_in[3];                 // [128, 1024]
    const float* b1  = (const float*)d_in[4];                 // [1024]
    const float* W2  = (const float*)d_in[5];                 // [1024, 64]
    const float* b2  = (const float*)d_in[6];                 // [64]
    float* out = (float*)d_out;                               // [N, 64]

    // workspace layout (float offsets), ~79 MB
    float* ws   = (float*)d_ws;
    float* dinv = ws;                                   // 100000
    float* norm = ws + 100096;                          // 400000
    float* xa   = ws + 500224;                          // 12.8M fp32
    float* t    = xa;                                   // overlays xa (dead after cvt)
    unsigned short* xab = (unsigned short*)(ws + 13300224);   // 12.8M bf16
    unsigned short* w1t = (unsigned short*)(ws + 19700224);   // 131072 bf16
    unsigned short* w2t = (unsigned short*)(ws + 19765760);   // 65536 bf16

    const int B = 256;

    // 1. degree (with self-loop) -> dinv -> norm
    init_deg_kernel<<<(N_NODES + B - 1) / B, B, 0, stream>>>(dinv, N_NODES);
    deg_accum_kernel<<<(N_EDGES + B - 1) / B, B, 0, stream>>>(dst, ew, dinv, N_EDGES);
    rsqrt_inplace_kernel<<<(N_NODES + B - 1) / B, B, 0, stream>>>(dinv, N_NODES);
    compute_norm_kernel<<<(N_EDGES + B - 1) / B, B, 0, stream>>>(src, dst, ew, dinv, norm, N_EDGES);

    // 2. layer-1 aggregation on raw x (fp32): xa = A_norm @ x
    {
        long total = (long)N_NODES << 7;
        selfloop_init_kernel<7><<<(int)((total + B - 1) / B), B, 0, stream>>>(dinv, x, nullptr, xa, N_NODES);
        total = (long)N_EDGES << 7;
        scatter_edges_kernel<7><<<(int)((total + B - 1) / B), B, 0, stream>>>(src, dst, norm, x, xa, N_EDGES);
    }

    // 3. conversions: xa->bf16, W1->W1T bf16, W2->W2T bf16
    {
        long n4 = ((long)N_NODES * IN_F) / 4;
        convert_x_kernel<<<(int)((n4 + B - 1) / B), B, 0, stream>>>(xa, xab, n4);
        convert_w1t_kernel<<<(IN_F * HID + B - 1) / B, B, 0, stream>>>(W1, w1t);
        convert_w2t_kernel<<<(HID * OUT_F + B - 1) / B, B, 0, stream>>>(W2, w2t);
    }

    // 4. t = relu(xab @ W1 + b1) @ W2   (fused MFMA, h never materialized)
    fused_mlp_mfma_kernel<<<(N_NODES + MLP_BM - 1) / MLP_BM, 256, 0, stream>>>(
        xab, w1t, b1, w2t, t, N_NODES);

    // 5. layer-2 aggregation on t (fp32): out = A_norm @ t + b2
    {
        long total = (long)N_NODES << 6;
        selfloop_init_kernel<6><<<(int)((total + B - 1) / B), B, 0, stream>>>(dinv, t, b2, out, N_NODES);
        total = (long)N_EDGES << 6;
        scatter_edges_kernel<6><<<(int)((total + B - 1) / B), B, 0, stream>>>(src, dst, norm, t, out, N_EDGES);
    }
}